// Round 12
// baseline (488.028 us; speedup 1.0000x reference)
//
#include <hip/hip_runtime.h>
#include <cstdint>
#include <cstddef>

#define M_ROWS 65536
#define N_COLS 1024
#define K_DIM  1024

typedef _Float16 f16x8 __attribute__((ext_vector_type(8)));
typedef float f32x4 __attribute__((ext_vector_type(4)));

// ---------------- prep: scale/bias ----------------
__global__ __launch_bounds__(256) void prep_scale_bias(
    const float* __restrict__ gamma, const float* __restrict__ beta,
    const float* __restrict__ mean, const float* __restrict__ var,
    float* __restrict__ bias, float* __restrict__ scale)
{
  int i = blockIdx.x * 256 + threadIdx.x;
  if (i < N_COLS) {
    float s = gamma[i] * rsqrtf(var[i] + 1e-3f);
    scale[i] = s;
    bias[i] = beta[i] - mean[i] * s;
  }
}

// ---------------- prep: W -> Bp (scaled f16, fragment-permuted for direct B loads) ----
// chunk = ((nb*16 + kt)*256 + ptid)*8 + qc*4 + kc*2 + fc   (16B chunks)
// ptid = wn*64 + g*16 + li, holding Wt[n][k..k+8] with
// n = nb*256 + wn*64 + qc*32 + fc*16 + li, k = kt*64 + kc*32 + g*8.
// => in the GEMM, a lane's 8 fragments for one ktile are contiguous 128B at
//    Bp + (nb*4096 + ptid)*128 + kt*32768, frag (qc,kc,fc) at immediate offset.
__global__ __launch_bounds__(256) void prep_bp(
    const float* __restrict__ W, const float* __restrict__ scale,
    char* __restrict__ Bp)
{
  __shared__ float tile[64][68];
  int k0 = blockIdx.x * 64, n0 = blockIdx.y * 64;
  int t = threadIdx.x;
  int kr = t >> 2, q = t & 3;
  #pragma unroll
  for (int j = 0; j < 4; ++j) {
    float4 v = *(const float4*)(W + (size_t)(k0 + kr) * N_COLS + n0 + q * 16 + j * 4);
    *(float4*)(&tile[kr][q * 16 + j * 4]) = v;
  }
  __syncthreads();
  int nr = t >> 2;
  int n = n0 + nr;
  float sn = scale[n];
  __align__(16) _Float16 h[16];
  #pragma unroll
  for (int j = 0; j < 16; ++j)
    h[j] = (_Float16)(tile[q * 16 + j][nr] * sn);   // h[j] = Wt[n][k0+q*16+j]
  int nb = n >> 8, wn = (n >> 6) & 3, qc = (n >> 5) & 1, fc = (n >> 4) & 1, li = n & 15;
  #pragma unroll
  for (int c = 0; c < 2; ++c) {
    int k = k0 + q * 16 + c * 8;
    int kt = k >> 6, kc = (k >> 5) & 1, g = (k >> 3) & 3;
    int ptid = wn * 64 + g * 16 + li;
    size_t chunk = ((size_t)(nb * 16 + kt) * 256 + ptid) * 8 + qc * 4 + kc * 2 + fc;
    *(uint4*)(Bp + chunk * 16) = *(const uint4*)(&h[c * 8]);
  }
}

// ---------------- prep: A (fp32) -> Af (f16), grid-stride, vectorized ----------------
__global__ __launch_bounds__(256) void conv_a_f16(
    const float* __restrict__ A, _Float16* __restrict__ Af)
{
  const size_t total8 = (size_t)M_ROWS * K_DIM / 8;
  size_t i = (size_t)blockIdx.x * 256 + threadIdx.x;
  const size_t stride = (size_t)gridDim.x * 256;
  for (; i < total8; i += stride) {
    float4 a = *(const float4*)(A + i * 8);
    float4 b = *(const float4*)(A + i * 8 + 4);
    union { _Float16 h[8]; uint4 u; } p;
    p.h[0] = (_Float16)a.x; p.h[1] = (_Float16)a.y;
    p.h[2] = (_Float16)a.z; p.h[3] = (_Float16)a.w;
    p.h[4] = (_Float16)b.x; p.h[5] = (_Float16)b.y;
    p.h[6] = (_Float16)b.z; p.h[7] = (_Float16)b.w;
    *(uint4*)(Af + i * 8) = p.u;
  }
}

// ---------------- 256x256 8-wave GEMM: A triple-buffered LDS, B direct from L2 ----------------
// 512 threads = 8 waves (2M x 4N); per wave 128x64 output, acc[8][4] in AGPRs.
// LDS 96 KB: 3 x (256x64 f16 A tile). Distance-2 A prefetch; top-of-body vmcnt(4)
// (only A(t+1)'s 4 loads newer than A(t)). B: fragment-permuted Bp, one per-lane
// base + immediate offsets, consumed by MFMA dependency waits (self-hiding).
template<int F16OUT>
__global__ __launch_bounds__(512, 2) void gemm_256d(
    const _Float16* __restrict__ Af, const char* __restrict__ Bp,
    const float* __restrict__ bias, const float* __restrict__ priors,
    void* __restrict__ zout)
{
  __shared__ char asmem[98304];   // 3 x 32KB A buffers
  const int tid = threadIdx.x;
  const int lane = tid & 63, wid = tid >> 6;
  const int wm = wid >> 2, wn = wid & 3;
  const int li = lane & 15, g = lane >> 4;

  // bijective XCD swizzle (nwg=1024, 1024%8==0)
  int orig = blockIdx.x;
  int wgid = (orig & 7) * 128 + (orig >> 3);
  int mb = wgid >> 2, nb = wgid & 3;
  const int m0 = mb * 256, n0 = nb * 256;

  f32x4 acc[8][4];
  #pragma unroll
  for (int i = 0; i < 8; ++i)
    #pragma unroll
    for (int j = 0; j < 4; ++j) acc[i][j] = (f32x4){0.f, 0.f, 0.f, 0.f};

  // A stage: 256x64 f16 tile = 2048 x 16B chunks, 4 per thread.
  // linear LDS dest + inverse-swizzled global source (rule 21).
  auto stageA = [&](int kt, int buf) {
    #pragma unroll
    for (int j = 0; j < 4; ++j) {
      int ch = j * 512 + tid;
      int rl = ch >> 3, c = ch & 7;
      const char* src = (const char*)Af + ((size_t)(m0 + rl) * K_DIM + kt * 64) * 2
                        + ((c * 16) ^ ((rl & 7) << 4));
      __builtin_amdgcn_global_load_lds(
          (const __attribute__((address_space(1))) unsigned int*)src,
          (__attribute__((address_space(3))) unsigned int*)(&asmem[buf * 32768 + ch * 16]),
          16, 0, 0);
    }
  };

  const char* bkt = Bp + ((size_t)nb * 4096 + wn * 64 + g * 16 + li) * 128;
  const int aswz = (li & 7) << 4;

  stageA(0, 0);
  stageA(1, 1);

  for (int t = 0; t < 16; ++t) {
    if (t < 15) asm volatile("s_waitcnt vmcnt(4)" ::: "memory");  // A(t) landed, A(t+1) in flight
    else        asm volatile("s_waitcnt vmcnt(0)" ::: "memory");
    __builtin_amdgcn_s_barrier();
    asm volatile("" ::: "memory");
    __builtin_amdgcn_sched_barrier(0);

    if (t < 14) stageA(t + 2, (t + 2) % 3);
    const int abase = (t % 3) * 32768;

    #pragma unroll
    for (int q = 0; q < 4; ++q) {
      const int qr = q >> 1, qc = q & 1;
      f16x8 af[4][2], bf[2][2];
      #pragma unroll
      for (int kc = 0; kc < 2; ++kc) {
        const int koff = (kc * 64 + g * 16) ^ aswz;
        #pragma unroll
        for (int fr = 0; fr < 4; ++fr) {
          int row = wm * 128 + qr * 64 + fr * 16 + li;
          af[fr][kc] = *(const f16x8*)(&asmem[abase + row * 128 + koff]);
        }
        #pragma unroll
        for (int fc = 0; fc < 2; ++fc)
          bf[fc][kc] = *(const f16x8*)(bkt + (qc * 4 + kc * 2 + fc) * 16);
      }
      __builtin_amdgcn_s_setprio(1);
      #pragma unroll
      for (int kc = 0; kc < 2; ++kc)
        #pragma unroll
        for (int fr = 0; fr < 4; ++fr)
          #pragma unroll
          for (int fc = 0; fc < 2; ++fc)
            acc[qr * 4 + fr][qc * 2 + fc] = __builtin_amdgcn_mfma_f32_16x16x32_f16(
                af[fr][kc], bf[fc][kc], acc[qr * 4 + fr][qc * 2 + fc], 0, 0, 0);
      __builtin_amdgcn_s_setprio(0);
    }
    bkt += 32768;

    asm volatile("s_waitcnt lgkmcnt(0)" ::: "memory"); // af reads retired
    __builtin_amdgcn_s_barrier();                      // buf (t%3) free for restage
    asm volatile("" ::: "memory");
    __builtin_amdgcn_sched_barrier(0);
  }

  // epilogue: z = (acc + bias) * priors -> f16 zh (or f32)
  float bv[4];
  #pragma unroll
  for (int j = 0; j < 4; ++j) bv[j] = bias[n0 + wn * 64 + j * 16 + li];
  #pragma unroll
  for (int i = 0; i < 8; ++i) {
    #pragma unroll
    for (int r = 0; r < 4; ++r) {
      size_t row = (size_t)(m0 + wm * 128 + i * 16 + g * 4 + r);
      const float* pp = priors + row * N_COLS + n0 + wn * 64 + li;
      #pragma unroll
      for (int j = 0; j < 4; ++j) {
        float z = (acc[i][j][r] + bv[j]) * pp[j * 16];
        size_t idx = row * N_COLS + n0 + wn * 64 + j * 16 + li;
        if (F16OUT) ((_Float16*)zout)[idx] = (_Float16)z;
        else        ((float*)zout)[idx] = z;
      }
    }
  }
}

// ---------------- sparsemax from f16 z -> f32 out, one wave per row ----------------
__global__ __launch_bounds__(256) void sparsemax_rows_h(
    const _Float16* __restrict__ zh, float* __restrict__ outp)
{
  const int lane = threadIdx.x & 63, wid = threadIdx.x >> 6;
  const size_t row = (size_t)blockIdx.x * 4 + wid;
  const _Float16* p = zh + row * N_COLS + lane * 16;

  f16x8 h0 = *(const f16x8*)(p);
  f16x8 h1 = *(const f16x8*)(p + 8);
  float v[16];
  #pragma unroll
  for (int j = 0; j < 8; ++j) { v[j] = (float)h0[j]; v[8 + j] = (float)h1[j]; }

  float mx = v[0];
  #pragma unroll
  for (int j = 1; j < 16; ++j) mx = fmaxf(mx, v[j]);
  #pragma unroll
  for (int m = 1; m <= 32; m <<= 1) mx = fmaxf(mx, __shfl_xor(mx, m, 64));

  float lo = mx - 1.0f, hi = mx;
  for (int it = 0; it < 12; ++it) {
    float tau = 0.5f * (lo + hi);
    float s = 0.f;
    #pragma unroll
    for (int j = 0; j < 16; ++j) s += fmaxf(v[j] - tau, 0.f);
    #pragma unroll
    for (int m = 1; m <= 32; m <<= 1) s += __shfl_xor(s, m, 64);
    if (s >= 1.f) lo = tau; else hi = tau;
  }
  float tau = lo;
  #pragma unroll
  for (int it = 0; it < 2; ++it) {
    float s = 0.f, k = 0.f;
    #pragma unroll
    for (int j = 0; j < 16; ++j) {
      bool g = v[j] > tau;
      s += g ? v[j] : 0.f;
      k += g ? 1.f : 0.f;
    }
    #pragma unroll
    for (int m = 1; m <= 32; m <<= 1) { s += __shfl_xor(s, m, 64); k += __shfl_xor(k, m, 64); }
    tau = (s - 1.f) / k;   // k >= 1 (row max stays in support)
  }

  float* o = outp + row * N_COLS + lane * 16;
  #pragma unroll
  for (int j = 0; j < 4; ++j) {
    float4 t;
    t.x = fmaxf(v[j * 4 + 0] - tau, 0.f);
    t.y = fmaxf(v[j * 4 + 1] - tau, 0.f);
    t.z = fmaxf(v[j * 4 + 2] - tau, 0.f);
    t.w = fmaxf(v[j * 4 + 3] - tau, 0.f);
    *(float4*)(o + j * 4) = t;
  }
}

// ---------------- sparsemax in place on f32 z (mid path) ----------------
__global__ __launch_bounds__(256) void sparsemax_rows(float* __restrict__ z)
{
  const int lane = threadIdx.x & 63, wid = threadIdx.x >> 6;
  const size_t row = (size_t)blockIdx.x * 4 + wid;
  float* p = z + row * N_COLS;
  float v[16];
  #pragma unroll
  for (int j = 0; j < 4; ++j) {
    float4 t = *(const float4*)(p + j * 256 + lane * 4);
    v[j * 4 + 0] = t.x; v[j * 4 + 1] = t.y; v[j * 4 + 2] = t.z; v[j * 4 + 3] = t.w;
  }
  float mx = v[0];
  #pragma unroll
  for (int j = 1; j < 16; ++j) mx = fmaxf(mx, v[j]);
  #pragma unroll
  for (int m = 1; m <= 32; m <<= 1) mx = fmaxf(mx, __shfl_xor(mx, m, 64));
  float lo = mx - 1.0f, hi = mx;
  for (int it = 0; it < 12; ++it) {
    float tau = 0.5f * (lo + hi);
    float s = 0.f;
    #pragma unroll
    for (int j = 0; j < 16; ++j) s += fmaxf(v[j] - tau, 0.f);
    #pragma unroll
    for (int m = 1; m <= 32; m <<= 1) s += __shfl_xor(s, m, 64);
    if (s >= 1.f) lo = tau; else hi = tau;
  }
  float tau = lo;
  #pragma unroll
  for (int it = 0; it < 2; ++it) {
    float s = 0.f, k = 0.f;
    #pragma unroll
    for (int j = 0; j < 16; ++j) {
      bool g = v[j] > tau;
      s += g ? v[j] : 0.f;
      k += g ? 1.f : 0.f;
    }
    #pragma unroll
    for (int m = 1; m <= 32; m <<= 1) { s += __shfl_xor(s, m, 64); k += __shfl_xor(k, m, 64); }
    tau = (s - 1.f) / k;
  }
  #pragma unroll
  for (int j = 0; j < 4; ++j) {
    float4 t;
    t.x = fmaxf(v[j * 4 + 0] - tau, 0.f);
    t.y = fmaxf(v[j * 4 + 1] - tau, 0.f);
    t.z = fmaxf(v[j * 4 + 2] - tau, 0.f);
    t.w = fmaxf(v[j * 4 + 3] - tau, 0.f);
    *(float4*)(p + j * 256 + lane * 4) = t;
  }
}

// ---------------- FALLBACK (tiny ws): R2 split kernels ----------------
__global__ __launch_bounds__(256) void prep_wt(
    const float* __restrict__ W, const float* __restrict__ scale,
    _Float16* __restrict__ Wt)
{
  __shared__ float tile[64][68];
  int k0 = blockIdx.x * 64, n0 = blockIdx.y * 64;
  int t = threadIdx.x;
  int kr = t >> 2, q = t & 3;
  #pragma unroll
  for (int j = 0; j < 4; ++j) {
    float4 v = *(const float4*)(W + (size_t)(k0 + kr) * N_COLS + n0 + q * 16 + j * 4);
    *(float4*)(&tile[kr][q * 16 + j * 4]) = v;
  }
  __syncthreads();
  int nr = t >> 2;
  float sn = scale[n0 + nr];
  __align__(16) _Float16 h[16];
  #pragma unroll
  for (int j = 0; j < 16; ++j)
    h[j] = (_Float16)(tile[q * 16 + j][nr] * sn);
  uint4* dst = (uint4*)(Wt + (size_t)(n0 + nr) * K_DIM + k0 + q * 16);
  dst[0] = *(uint4*)(&h[0]);
  dst[1] = *(uint4*)(&h[8]);
}

__global__ __launch_bounds__(256, 2) void gemm_f16(
    const float* __restrict__ A, const _Float16* __restrict__ Wt,
    const float* __restrict__ bias, const float* __restrict__ priors,
    float* __restrict__ out)
{
  __shared__ char smem[65536];
  const int tid = threadIdx.x;
  const int lane = tid & 63, wid = tid >> 6;
  const int wm = wid >> 1, wnn = wid & 1;
  int orig = blockIdx.x;
  int wgid = (orig & 7) * 512 + (orig >> 3);
  int mb = wgid >> 3, nb = wgid & 7;
  const int m0 = mb * 128, n0 = nb * 128;
  f32x4 acc[4][4];
  #pragma unroll
  for (int i = 0; i < 4; ++i)
    #pragma unroll
    for (int j = 0; j < 4; ++j) acc[i][j] = (f32x4){0.f, 0.f, 0.f, 0.f};
  float4 areg[8];
  auto loadA = [&](int kt) {
    #pragma unroll
    for (int j = 0; j < 8; ++j) {
      int f = j * 256 + tid;
      int ml = f >> 4, k4 = (f & 15) << 2;
      areg[j] = *(const float4*)(A + (size_t)(m0 + ml) * K_DIM + kt * 64 + k4);
    }
  };
  auto storeA = [&](int buf) {
    int base = buf * 16384;
    #pragma unroll
    for (int j = 0; j < 8; ++j) {
      int f = j * 256 + tid;
      int ml = f >> 4, k4 = (f & 15) << 2;
      int off = ml * 128 + ((k4 * 2) ^ ((ml & 7) << 4));
      union { _Float16 h[4]; uint2 u; } p;
      p.h[0] = (_Float16)areg[j].x; p.h[1] = (_Float16)areg[j].y;
      p.h[2] = (_Float16)areg[j].z; p.h[3] = (_Float16)areg[j].w;
      *(uint2*)(&smem[base + off]) = p.u;
    }
  };
  auto issueB = [&](int kt, int buf) {
    int base = 32768 + buf * 16384;
    #pragma unroll
    for (int t4 = 0; t4 < 4; ++t4) {
      int ch = t4 * 256 + tid;
      int nl = ch >> 3, c = ch & 7;
      const char* src = (const char*)Wt + ((size_t)(n0 + nl) * K_DIM + kt * 64) * 2
          + ((c * 16) ^ ((nl & 7) << 4));
      __builtin_amdgcn_global_load_lds(
          (const __attribute__((address_space(1))) unsigned int*)src,
          (__attribute__((address_space(3))) unsigned int*)(&smem[base + ch * 16]),
          16, 0, 0);
    }
  };
  loadA(0); issueB(0, 0); storeA(0);
  __syncthreads();
  for (int kt = 0; kt < 16; ++kt) {
    int curb = kt & 1, nxt = curb ^ 1;
    if (kt < 15) { loadA(kt + 1); issueB(kt + 1, nxt); }
    int ab = curb * 16384, bb = 32768 + curb * 16384;
    #pragma unroll
    for (int kc = 0; kc < 2; ++kc) {
      int k2 = (kc * 32 + ((lane >> 4) * 8)) * 2;
      f16x8 af[4], bfr[4];
      #pragma unroll
      for (int fm = 0; fm < 4; ++fm) {
        int rl2 = wm * 64 + fm * 16 + (lane & 15);
        af[fm] = *(const f16x8*)(&smem[ab + rl2 * 128 + (k2 ^ ((rl2 & 7) << 4))]);
      }
      #pragma unroll
      for (int fn = 0; fn < 4; ++fn) {
        int nl = wnn * 64 + fn * 16 + (lane & 15);
        bfr[fn] = *(const f16x8*)(&smem[bb + nl * 128 + (k2 ^ ((nl & 7) << 4))]);
      }
      #pragma unroll
      for (int fm = 0; fm < 4; ++fm)
        #pragma unroll
        for (int fn = 0; fn < 4; ++fn)
          acc[fm][fn] = __builtin_amdgcn_mfma_f32_16x16x32_f16(af[fm], bfr[fn], acc[fm][fn], 0, 0, 0);
    }
    if (kt < 15) storeA(nxt);
    __syncthreads();
  }
  #pragma unroll
  for (int fn = 0; fn < 4; ++fn) {
    int col = n0 + wnn * 64 + fn * 16 + (lane & 15);
    float bvv = bias[col];
    #pragma unroll
    for (int fm = 0; fm < 4; ++fm) {
      int row0 = m0 + wm * 64 + fm * 16 + ((lane >> 4) << 2);
      #pragma unroll
      for (int r = 0; r < 4; ++r) {
        size_t idx = (size_t)(row0 + r) * N_COLS + col;
        out[idx] = (acc[fm][fn][r] + bvv) * priors[idx];
      }
    }
  }
}

// ---------------- launch ----------------
extern "C" void kernel_launch(void* const* d_in, const int* in_sizes, int n_in,
                              void* d_out, int out_size, void* d_ws, size_t ws_size,
                              hipStream_t stream) {
  const float* inputs = (const float*)d_in[0];
  const float* priors = (const float*)d_in[1];
  const float* W      = (const float*)d_in[2];
  const float* gamma  = (const float*)d_in[3];
  const float* beta   = (const float*)d_in[4];
  const float* mean   = (const float*)d_in[5];
  const float* var    = (const float*)d_in[6];
  float* out = (float*)d_out;

  char* ws = (char*)d_ws;
  float* bias  = (float*)ws;                 // 4 KB
  float* scale = (float*)(ws + 4096);        // 4 KB
  char*  Bp    = ws + 8192;                  // 2 MB: fragment-permuted Bp (or Wt for fallback)
  const size_t AF_OFF = 8192 + (size_t)N_COLS * K_DIM * 2;          // 2105344
  _Float16* Af = (_Float16*)(ws + AF_OFF);   // 134 MB, [M][K] f16
  const size_t ZH_OFF = AF_OFF + (size_t)M_ROWS * K_DIM * 2;        // 136323072
  _Float16* zh = (_Float16*)(ws + ZH_OFF);   // 134 MB, [M][N] f16 z
  const size_t need  = ZH_OFF;
  const size_t need2 = ZH_OFF + (size_t)M_ROWS * N_COLS * 2;

  prep_scale_bias<<<4, 256, 0, stream>>>(gamma, beta, mean, var, bias, scale);

  if (ws_size >= need2) {
    prep_bp<<<dim3(16, 16), 256, 0, stream>>>(W, scale, Bp);
    conv_a_f16<<<2048, 256, 0, stream>>>(inputs, Af);
    gemm_256d<1><<<1024, 512, 0, stream>>>(Af, Bp, bias, priors, zh);
    sparsemax_rows_h<<<16384, 256, 0, stream>>>(zh, out);
  } else if (ws_size >= need) {
    prep_bp<<<dim3(16, 16), 256, 0, stream>>>(W, scale, Bp);
    conv_a_f16<<<2048, 256, 0, stream>>>(inputs, Af);
    gemm_256d<0><<<1024, 512, 0, stream>>>(Af, Bp, bias, priors, out);
    sparsemax_rows<<<16384, 256, 0, stream>>>(out);
  } else {
    prep_wt<<<dim3(16, 16), 256, 0, stream>>>(W, scale, (_Float16*)Bp);
    gemm_f16<<<4096, 256, 0, stream>>>(inputs, (_Float16*)Bp, bias, priors, out);
    sparsemax_rows<<<16384, 256, 0, stream>>>(out);
  }
}

// Round 13
// 408.807 us; speedup vs baseline: 1.1938x; 1.1938x over previous
//
#include <hip/hip_runtime.h>
#include <cstdint>
#include <cstddef>

#define M_ROWS 65536
#define N_COLS 1024
#define K_DIM  1024

typedef _Float16 f16x8 __attribute__((ext_vector_type(8)));
typedef float f32x4 __attribute__((ext_vector_type(4)));

// ---------------- prep: scale/bias ----------------
__global__ __launch_bounds__(256) void prep_scale_bias(
    const float* __restrict__ gamma, const float* __restrict__ beta,
    const float* __restrict__ mean, const float* __restrict__ var,
    float* __restrict__ bias, float* __restrict__ scale)
{
  int i = blockIdx.x * 256 + threadIdx.x;
  if (i < N_COLS) {
    float s = gamma[i] * rsqrtf(var[i] + 1e-3f);
    scale[i] = s;
    bias[i] = beta[i] - mean[i] * s;
  }
}

// ---------------- prep: W -> Wt (transposed, scaled, f16) ----------------
__global__ __launch_bounds__(256) void prep_wt(
    const float* __restrict__ W, const float* __restrict__ scale,
    _Float16* __restrict__ Wt)
{
  __shared__ float tile[64][68];
  int k0 = blockIdx.x * 64, n0 = blockIdx.y * 64;
  int t = threadIdx.x;
  int kr = t >> 2, q = t & 3;
  #pragma unroll
  for (int j = 0; j < 4; ++j) {
    float4 v = *(const float4*)(W + (size_t)(k0 + kr) * N_COLS + n0 + q * 16 + j * 4);
    *(float4*)(&tile[kr][q * 16 + j * 4]) = v;
  }
  __syncthreads();
  int nr = t >> 2;
  float sn = scale[n0 + nr];
  __align__(16) _Float16 h[16];
  #pragma unroll
  for (int j = 0; j < 16; ++j)
    h[j] = (_Float16)(tile[q * 16 + j][nr] * sn);
  uint4* dst = (uint4*)(Wt + (size_t)(n0 + nr) * K_DIM + k0 + q * 16);
  dst[0] = *(uint4*)(&h[0]);
  dst[1] = *(uint4*)(&h[8]);
}

// ---------------- prep: A (fp32) -> Af (f16), grid-stride, vectorized ----------------
__global__ __launch_bounds__(256) void conv_a_f16(
    const float* __restrict__ A, _Float16* __restrict__ Af)
{
  const size_t total8 = (size_t)M_ROWS * K_DIM / 8;
  size_t i = (size_t)blockIdx.x * 256 + threadIdx.x;
  const size_t stride = (size_t)gridDim.x * 256;
  for (; i < total8; i += stride) {
    float4 a = *(const float4*)(A + i * 8);
    float4 b = *(const float4*)(A + i * 8 + 4);
    union { _Float16 h[8]; uint4 u; } p;
    p.h[0] = (_Float16)a.x; p.h[1] = (_Float16)a.y;
    p.h[2] = (_Float16)a.z; p.h[3] = (_Float16)a.w;
    p.h[4] = (_Float16)b.x; p.h[5] = (_Float16)b.y;
    p.h[6] = (_Float16)b.z; p.h[7] = (_Float16)b.w;
    *(uint4*)(Af + i * 8) = p.u;
  }
}

// ---------------- 256x256 8-wave GEMM, 4-phase/K-tile m201-style interleave ----------------
// 512 threads = 8 waves (2M x 4N); per wave 128x64 output, acc[8][4] in AGPRs.
// LDS 128 KB dbuf; per K-tile 4 quadrant-phases, each:
//   {ds_reads (af 8 on qr-change + bf 4); stage 1/4 of K-tile t+1 (A@q0, B@q1);
//    barrier; lgkmcnt(0)+sched_barrier; setprio(1); 16 MFMA; setprio(0); barrier}
// Staging only in phases 0-1 -> at next iteration top the outstanding loads are
// >=2 phases old (~700cyc cover >= L3), so the single vmcnt(0) is nearly free.
template<int F16OUT>
__global__ __launch_bounds__(512, 2) void gemm_256p(
    const _Float16* __restrict__ Af, const _Float16* __restrict__ Wt,
    const float* __restrict__ bias, const float* __restrict__ priors,
    void* __restrict__ zout)
{
  __shared__ char smem[131072];   // buf d: A @ d*65536 (32KB), B @ d*65536+32768 (32KB)
  const int tid = threadIdx.x;
  const int lane = tid & 63, wid = tid >> 6;
  const int wm = wid >> 2, wn = wid & 3;
  const int li = lane & 15, g = lane >> 4;

  // bijective XCD swizzle (nwg=1024, 1024%8==0)
  int orig = blockIdx.x;
  int wgid = (orig & 7) * 128 + (orig >> 3);
  int mb = wgid >> 2, nb = wgid & 3;
  const int m0 = mb * 256, n0 = nb * 256;

  f32x4 acc[8][4];
  #pragma unroll
  for (int i = 0; i < 8; ++i)
    #pragma unroll
    for (int j = 0; j < 4; ++j) acc[i][j] = (f32x4){0.f, 0.f, 0.f, 0.f};

  // stage 256x64 f16 tile = 2048 x 16B chunks, 4 per thread (rule 21 source swizzle)
  auto stageA = [&](int kt, int buf) {
    #pragma unroll
    for (int j = 0; j < 4; ++j) {
      int ch = j * 512 + tid;
      int rl = ch >> 3, c = ch & 7;
      const char* src = (const char*)Af + ((size_t)(m0 + rl) * K_DIM + kt * 64) * 2
                        + ((c * 16) ^ ((rl & 7) << 4));
      __builtin_amdgcn_global_load_lds(
          (const __attribute__((address_space(1))) unsigned int*)src,
          (__attribute__((address_space(3))) unsigned int*)(&smem[buf * 65536 + ch * 16]),
          16, 0, 0);
    }
  };
  auto stageB = [&](int kt, int buf) {
    #pragma unroll
    for (int j = 0; j < 4; ++j) {
      int ch = j * 512 + tid;
      int cl = ch >> 3, c = ch & 7;
      const char* src = (const char*)Wt + ((size_t)(n0 + cl) * K_DIM + kt * 64) * 2
                        + ((c * 16) ^ ((cl & 7) << 4));
      __builtin_amdgcn_global_load_lds(
          (const __attribute__((address_space(1))) unsigned int*)src,
          (__attribute__((address_space(3))) unsigned int*)(&smem[buf * 65536 + 32768 + ch * 16]),
          16, 0, 0);
    }
  };

  const int aswz = (li & 7) << 4;

  stageA(0, 0);
  stageB(0, 0);

  f16x8 af[4][2], bf[2][2];

  for (int t = 0; t < 16; ++t) {
    const int d = t & 1;
    const int abase = d * 65536, bbase = d * 65536 + 32768;

    // K-tile t fully landed (its loads are the oldest; staged >=2 phases ago)
    asm volatile("s_waitcnt vmcnt(0)" ::: "memory");
    __builtin_amdgcn_s_barrier();
    asm volatile("" ::: "memory");
    __builtin_amdgcn_sched_barrier(0);

    #pragma unroll
    for (int q = 0; q < 4; ++q) {
      const int qr = q >> 1, qc = q & 1;
      // af refresh on qr change (phases 0 and 2)
      if (qc == 0) {
        #pragma unroll
        for (int kc = 0; kc < 2; ++kc) {
          const int koff = (kc * 64 + g * 16) ^ aswz;
          #pragma unroll
          for (int fr = 0; fr < 4; ++fr) {
            int row = wm * 128 + qr * 64 + fr * 16 + li;
            af[fr][kc] = *(const f16x8*)(&smem[abase + row * 128 + koff]);
          }
        }
      }
      // bf every phase
      #pragma unroll
      for (int kc = 0; kc < 2; ++kc) {
        const int koff = (kc * 64 + g * 16) ^ aswz;
        #pragma unroll
        for (int fc = 0; fc < 2; ++fc) {
          int col = wn * 64 + qc * 32 + fc * 16 + li;
          bf[fc][kc] = *(const f16x8*)(&smem[bbase + col * 128 + koff]);
        }
      }
      // stage K-tile t+1 in the first two phases only
      if (t < 15) {
        if (q == 0) stageA(t + 1, d ^ 1);
        if (q == 1) stageB(t + 1, d ^ 1);
      }
      __builtin_amdgcn_s_barrier();
      asm volatile("s_waitcnt lgkmcnt(0)" ::: "memory");
      __builtin_amdgcn_sched_barrier(0);
      __builtin_amdgcn_s_setprio(1);
      #pragma unroll
      for (int kc = 0; kc < 2; ++kc)
        #pragma unroll
        for (int fr = 0; fr < 4; ++fr)
          #pragma unroll
          for (int fc = 0; fc < 2; ++fc)
            acc[qr * 4 + fr][qc * 2 + fc] = __builtin_amdgcn_mfma_f32_16x16x32_f16(
                af[fr][kc], bf[fc][kc], acc[qr * 4 + fr][qc * 2 + fc], 0, 0, 0);
      __builtin_amdgcn_s_setprio(0);
      __builtin_amdgcn_s_barrier();
    }
  }

  // epilogue: z = (acc + bias) * priors -> f16 zh (or f32)
  float bv[4];
  #pragma unroll
  for (int j = 0; j < 4; ++j) bv[j] = bias[n0 + wn * 64 + j * 16 + li];
  #pragma unroll
  for (int i = 0; i < 8; ++i) {
    #pragma unroll
    for (int r = 0; r < 4; ++r) {
      size_t row = (size_t)(m0 + wm * 128 + i * 16 + g * 4 + r);
      const float* pp = priors + row * N_COLS + n0 + wn * 64 + li;
      #pragma unroll
      for (int j = 0; j < 4; ++j) {
        float z = (acc[i][j][r] + bv[j]) * pp[j * 16];
        size_t idx = row * N_COLS + n0 + wn * 64 + j * 16 + li;
        if (F16OUT) ((_Float16*)zout)[idx] = (_Float16)z;
        else        ((float*)zout)[idx] = z;
      }
    }
  }
}

// ---------------- sparsemax from f16 z -> f32 out, one wave per row ----------------
__global__ __launch_bounds__(256) void sparsemax_rows_h(
    const _Float16* __restrict__ zh, float* __restrict__ outp)
{
  const int lane = threadIdx.x & 63, wid = threadIdx.x >> 6;
  const size_t row = (size_t)blockIdx.x * 4 + wid;
  const _Float16* p = zh + row * N_COLS + lane * 16;

  f16x8 h0 = *(const f16x8*)(p);
  f16x8 h1 = *(const f16x8*)(p + 8);
  float v[16];
  #pragma unroll
  for (int j = 0; j < 8; ++j) { v[j] = (float)h0[j]; v[8 + j] = (float)h1[j]; }

  float mx = v[0];
  #pragma unroll
  for (int j = 1; j < 16; ++j) mx = fmaxf(mx, v[j]);
  #pragma unroll
  for (int m = 1; m <= 32; m <<= 1) mx = fmaxf(mx, __shfl_xor(mx, m, 64));

  float lo = mx - 1.0f, hi = mx;
  for (int it = 0; it < 12; ++it) {
    float tau = 0.5f * (lo + hi);
    float s = 0.f;
    #pragma unroll
    for (int j = 0; j < 16; ++j) s += fmaxf(v[j] - tau, 0.f);
    #pragma unroll
    for (int m = 1; m <= 32; m <<= 1) s += __shfl_xor(s, m, 64);
    if (s >= 1.f) lo = tau; else hi = tau;
  }
  float tau = lo;
  #pragma unroll
  for (int it = 0; it < 2; ++it) {
    float s = 0.f, k = 0.f;
    #pragma unroll
    for (int j = 0; j < 16; ++j) {
      bool g = v[j] > tau;
      s += g ? v[j] : 0.f;
      k += g ? 1.f : 0.f;
    }
    #pragma unroll
    for (int m = 1; m <= 32; m <<= 1) { s += __shfl_xor(s, m, 64); k += __shfl_xor(k, m, 64); }
    tau = (s - 1.f) / k;   // k >= 1 (row max stays in support)
  }

  float* o = outp + row * N_COLS + lane * 16;
  #pragma unroll
  for (int j = 0; j < 4; ++j) {
    float4 t;
    t.x = fmaxf(v[j * 4 + 0] - tau, 0.f);
    t.y = fmaxf(v[j * 4 + 1] - tau, 0.f);
    t.z = fmaxf(v[j * 4 + 2] - tau, 0.f);
    t.w = fmaxf(v[j * 4 + 3] - tau, 0.f);
    *(float4*)(o + j * 4) = t;
  }
}

// ---------------- sparsemax in place on f32 z (mid path) ----------------
__global__ __launch_bounds__(256) void sparsemax_rows(float* __restrict__ z)
{
  const int lane = threadIdx.x & 63, wid = threadIdx.x >> 6;
  const size_t row = (size_t)blockIdx.x * 4 + wid;
  float* p = z + row * N_COLS;
  float v[16];
  #pragma unroll
  for (int j = 0; j < 4; ++j) {
    float4 t = *(const float4*)(p + j * 256 + lane * 4);
    v[j * 4 + 0] = t.x; v[j * 4 + 1] = t.y; v[j * 4 + 2] = t.z; v[j * 4 + 3] = t.w;
  }
  float mx = v[0];
  #pragma unroll
  for (int j = 1; j < 16; ++j) mx = fmaxf(mx, v[j]);
  #pragma unroll
  for (int m = 1; m <= 32; m <<= 1) mx = fmaxf(mx, __shfl_xor(mx, m, 64));
  float lo = mx - 1.0f, hi = mx;
  for (int it = 0; it < 12; ++it) {
    float tau = 0.5f * (lo + hi);
    float s = 0.f;
    #pragma unroll
    for (int j = 0; j < 16; ++j) s += fmaxf(v[j] - tau, 0.f);
    #pragma unroll
    for (int m = 1; m <= 32; m <<= 1) s += __shfl_xor(s, m, 64);
    if (s >= 1.f) lo = tau; else hi = tau;
  }
  float tau = lo;
  #pragma unroll
  for (int it = 0; it < 2; ++it) {
    float s = 0.f, k = 0.f;
    #pragma unroll
    for (int j = 0; j < 16; ++j) {
      bool g = v[j] > tau;
      s += g ? v[j] : 0.f;
      k += g ? 1.f : 0.f;
    }
    #pragma unroll
    for (int m = 1; m <= 32; m <<= 1) { s += __shfl_xor(s, m, 64); k += __shfl_xor(k, m, 64); }
    tau = (s - 1.f) / k;
  }
  #pragma unroll
  for (int j = 0; j < 4; ++j) {
    float4 t;
    t.x = fmaxf(v[j * 4 + 0] - tau, 0.f);
    t.y = fmaxf(v[j * 4 + 1] - tau, 0.f);
    t.z = fmaxf(v[j * 4 + 2] - tau, 0.f);
    t.w = fmaxf(v[j * 4 + 3] - tau, 0.f);
    *(float4*)(p + j * 256 + lane * 4) = t;
  }
}

// ---------------- FALLBACK GEMM (tiny ws): A reg-staged fp32->f16, dbuf ----------------
__global__ __launch_bounds__(256, 2) void gemm_f16(
    const float* __restrict__ A, const _Float16* __restrict__ Wt,
    const float* __restrict__ bias, const float* __restrict__ priors,
    float* __restrict__ out)
{
  __shared__ char smem[65536];
  const int tid = threadIdx.x;
  const int lane = tid & 63, wid = tid >> 6;
  const int wm = wid >> 1, wnn = wid & 1;
  int orig = blockIdx.x;
  int wgid = (orig & 7) * 512 + (orig >> 3);
  int mb = wgid >> 3, nb = wgid & 7;
  const int m0 = mb * 128, n0 = nb * 128;
  f32x4 acc[4][4];
  #pragma unroll
  for (int i = 0; i < 4; ++i)
    #pragma unroll
    for (int j = 0; j < 4; ++j) acc[i][j] = (f32x4){0.f, 0.f, 0.f, 0.f};
  float4 areg[8];
  auto loadA = [&](int kt) {
    #pragma unroll
    for (int j = 0; j < 8; ++j) {
      int f = j * 256 + tid;
      int ml = f >> 4, k4 = (f & 15) << 2;
      areg[j] = *(const float4*)(A + (size_t)(m0 + ml) * K_DIM + kt * 64 + k4);
    }
  };
  auto storeA = [&](int buf) {
    int base = buf * 16384;
    #pragma unroll
    for (int j = 0; j < 8; ++j) {
      int f = j * 256 + tid;
      int ml = f >> 4, k4 = (f & 15) << 2;
      int off = ml * 128 + ((k4 * 2) ^ ((ml & 7) << 4));
      union { _Float16 h[4]; uint2 u; } p;
      p.h[0] = (_Float16)areg[j].x; p.h[1] = (_Float16)areg[j].y;
      p.h[2] = (_Float16)areg[j].z; p.h[3] = (_Float16)areg[j].w;
      *(uint2*)(&smem[base + off]) = p.u;
    }
  };
  auto issueB = [&](int kt, int buf) {
    int base = 32768 + buf * 16384;
    #pragma unroll
    for (int t4 = 0; t4 < 4; ++t4) {
      int ch = t4 * 256 + tid;
      int nl = ch >> 3, c = ch & 7;
      const char* src = (const char*)Wt + ((size_t)(n0 + nl) * K_DIM + kt * 64) * 2
          + ((c * 16) ^ ((nl & 7) << 4));
      __builtin_amdgcn_global_load_lds(
          (const __attribute__((address_space(1))) unsigned int*)src,
          (__attribute__((address_space(3))) unsigned int*)(&smem[base + ch * 16]),
          16, 0, 0);
    }
  };
  loadA(0); issueB(0, 0); storeA(0);
  __syncthreads();
  for (int kt = 0; kt < 16; ++kt) {
    int curb = kt & 1, nxt = curb ^ 1;
    if (kt < 15) { loadA(kt + 1); issueB(kt + 1, nxt); }
    int ab = curb * 16384, bb = 32768 + curb * 16384;
    #pragma unroll
    for (int kc = 0; kc < 2; ++kc) {
      int k2 = (kc * 32 + ((lane >> 4) * 8)) * 2;
      f16x8 af[4], bfr[4];
      #pragma unroll
      for (int fm = 0; fm < 4; ++fm) {
        int rl2 = wm * 64 + fm * 16 + (lane & 15);
        af[fm] = *(const f16x8*)(&smem[ab + rl2 * 128 + (k2 ^ ((rl2 & 7) << 4))]);
      }
      #pragma unroll
      for (int fn = 0; fn < 4; ++fn) {
        int nl = wnn * 64 + fn * 16 + (lane & 15);
        bfr[fn] = *(const f16x8*)(&smem[bb + nl * 128 + (k2 ^ ((nl & 7) << 4))]);
      }
      #pragma unroll
      for (int fm = 0; fm < 4; ++fm)
        #pragma unroll
        for (int fn = 0; fn < 4; ++fn)
          acc[fm][fn] = __builtin_amdgcn_mfma_f32_16x16x32_f16(af[fm], bfr[fn], acc[fm][fn], 0, 0, 0);
    }
    if (kt < 15) storeA(nxt);
    __syncthreads();
  }
  #pragma unroll
  for (int fn = 0; fn < 4; ++fn) {
    int col = n0 + wnn * 64 + fn * 16 + (lane & 15);
    float bvv = bias[col];
    #pragma unroll
    for (int fm = 0; fm < 4; ++fm) {
      int row0 = m0 + wm * 64 + fm * 16 + ((lane >> 4) << 2);
      #pragma unroll
      for (int r = 0; r < 4; ++r) {
        size_t idx = (size_t)(row0 + r) * N_COLS + col;
        out[idx] = (acc[fm][fn][r] + bvv) * priors[idx];
      }
    }
  }
}

// ---------------- launch ----------------
extern "C" void kernel_launch(void* const* d_in, const int* in_sizes, int n_in,
                              void* d_out, int out_size, void* d_ws, size_t ws_size,
                              hipStream_t stream) {
  const float* inputs = (const float*)d_in[0];
  const float* priors = (const float*)d_in[1];
  const float* W      = (const float*)d_in[2];
  const float* gamma  = (const float*)d_in[3];
  const float* beta   = (const float*)d_in[4];
  const float* mean   = (const float*)d_in[5];
  const float* var    = (const float*)d_in[6];
  float* out = (float*)d_out;

  char* ws = (char*)d_ws;
  float* bias  = (float*)ws;                 // 4 KB
  float* scale = (float*)(ws + 4096);        // 4 KB
  _Float16* Wt = (_Float16*)(ws + 8192);     // 2 MB, [N][K] transposed+scaled
  const size_t AF_OFF = 8192 + (size_t)N_COLS * K_DIM * 2;          // 2105344
  _Float16* Af = (_Float16*)(ws + AF_OFF);   // 134 MB, [M][K] f16
  const size_t ZH_OFF = AF_OFF + (size_t)M_ROWS * K_DIM * 2;        // 136323072
  _Float16* zh = (_Float16*)(ws + ZH_OFF);   // 134 MB, [M][N] f16 z
  const size_t need  = ZH_OFF;
  const size_t need2 = ZH_OFF + (size_t)M_ROWS * N_COLS * 2;

  prep_scale_bias<<<4, 256, 0, stream>>>(gamma, beta, mean, var, bias, scale);
  prep_wt<<<dim3(16, 16), 256, 0, stream>>>(W, scale, Wt);

  if (ws_size >= need2) {
    conv_a_f16<<<2048, 256, 0, stream>>>(inputs, Af);
    gemm_256p<1><<<1024, 512, 0, stream>>>(Af, Wt, bias, priors, zh);
    sparsemax_rows_h<<<16384, 256, 0, stream>>>(zh, out);
  } else if (ws_size >= need) {
    conv_a_f16<<<2048, 256, 0, stream>>>(inputs, Af);
    gemm_256p<0><<<1024, 512, 0, stream>>>(Af, Wt, bias, priors, out);
    sparsemax_rows<<<16384, 256, 0, stream>>>(out);
  } else {
    gemm_f16<<<4096, 256, 0, stream>>>(inputs, Wt, bias, priors, out);
    sparsemax_rows<<<16384, 256, 0, stream>>>(out);
  }
}